// Round 7
// baseline (12532.922 us; speedup 1.0000x reference)
//
#include <hip/hip_runtime.h>

// SimpleRNN: 2-layer ReLU RNN, B=64 T=512 I=256 H=1024 O=1000, fp32 in/out.
// Round 7: multi-kernel scan — one launch per time step (513 total), each
// computing L0-step k and L1-step (k-1). All recurrent state moves through
// PLAIN loads/stores with kernel-boundary coherence (proven primitive);
// no polls, fences, atomics, or sc-bit assumptions. Graph replay prices each
// step at (node gap + ~1us exec).

typedef float f32x4 __attribute__((ext_vector_type(4)));
typedef short bf16x8 __attribute__((ext_vector_type(8)));
typedef unsigned short u16;
typedef unsigned int u32;
typedef u32 u32x4 __attribute__((ext_vector_type(4)));

#define MFMA_BF16(a, b, c) __builtin_amdgcn_mfma_f32_16x16x32_bf16((a), (b), (c), 0, 0, 0)

#define GLDS16(g, l) __builtin_amdgcn_global_load_lds( \
    (const __attribute__((address_space(1))) unsigned int*)(g), \
    (__attribute__((address_space(3))) unsigned int*)(l), 16, 0, 0)

__device__ __forceinline__ u16 f2b(float f) {  // RNE f32 -> bf16 bits
  unsigned int u = __builtin_bit_cast(unsigned int, f);
  u = (u + 0x7fffu + ((u >> 16) & 1u)) >> 16;
  return (u16)u;
}
__device__ __forceinline__ float b2f(u16 b) {
  unsigned int u = ((unsigned int)b) << 16;
  return __builtin_bit_cast(float, u);
}

// packed u32 = hi-bf16 (low16) | lo-bf16 (high16); extract 8-elem bf16 frags
__device__ __forceinline__ bf16x8 hi_frag(u32x4 d0, u32x4 d1) {
  u32x4 r;
  r[0] = __builtin_amdgcn_perm(d0[1], d0[0], 0x05040100u);
  r[1] = __builtin_amdgcn_perm(d0[3], d0[2], 0x05040100u);
  r[2] = __builtin_amdgcn_perm(d1[1], d1[0], 0x05040100u);
  r[3] = __builtin_amdgcn_perm(d1[3], d1[2], 0x05040100u);
  return __builtin_bit_cast(bf16x8, r);
}
__device__ __forceinline__ bf16x8 lo_frag(u32x4 d0, u32x4 d1) {
  u32x4 r;
  r[0] = __builtin_amdgcn_perm(d0[1], d0[0], 0x07060302u);
  r[1] = __builtin_amdgcn_perm(d0[3], d0[2], 0x07060302u);
  r[2] = __builtin_amdgcn_perm(d1[1], d1[0], 0x07060302u);
  r[3] = __builtin_amdgcn_perm(d1[3], d1[2], 0x07060302u);
  return __builtin_bit_cast(bf16x8, r);
}

// ---------------- elementwise helpers ----------------
__global__ void cast_kernel(const float* __restrict__ s, u16* __restrict__ d, int n4) {
  int i = blockIdx.x * blockDim.x + threadIdx.x;
  if (i >= n4) return;
  float4 v = ((const float4*)s)[i];
  ushort4 o;
  o.x = f2b(v.x); o.y = f2b(v.y); o.z = f2b(v.z); o.w = f2b(v.w);
  ((ushort4*)d)[i] = o;
}

__global__ void bias_kernel(const float* __restrict__ a, const float* __restrict__ b,
                            float* __restrict__ o, int n) {
  int i = blockIdx.x * blockDim.x + threadIdx.x;
  if (i < n) o[i] = a[i] + b[i];
}

// zero slot 1 of both h rings (h(-1) = 0); plain stores, kernel-boundary coherent
__global__ void init_ring_kernel(u32* __restrict__ h0, u32* __restrict__ h1) {
  int i = blockIdx.x * blockDim.x + threadIdx.x;  // 0..65535
  h0[65536 + i] = 0;
  h1[65536 + i] = 0;
}

// ---------------- input GEMM: pre = A @ Bw^T  (A:[M][K], Bw:[1024][K]) ----------------
// rows m=b*512+t -> out row t*64+b (time-major). Out: bf16 [32768][1024].
__global__ __launch_bounds__(256) void gemm_pre(const u16* __restrict__ A,
                                                const u16* __restrict__ Bw,
                                                u16* __restrict__ outp, int K) {
  __shared__ u16 As[128 * 32];
  __shared__ u16 Bs[128 * 32];
  const int tid = threadIdx.x;
  const int lane = tid & 63;
  const int w = tid >> 6;
  const int nt = blockIdx.x & 7;
  const int mt = blockIdx.x >> 3;
  const int m_base = mt * 128;
  const int n_base = nt * 128;

  const int srow = w * 32 + (lane >> 2);
  const int schunk = (lane & 3) ^ (srow & 3);
  const u16* Ag0 = A + (size_t)(m_base + srow) * K + schunk * 8;
  const u16* Ag1 = A + (size_t)(m_base + srow + 16) * K + schunk * 8;
  const u16* Bg0 = Bw + (size_t)(n_base + srow) * K + schunk * 8;
  const u16* Bg1 = Bw + (size_t)(n_base + srow + 16) * K + schunk * 8;
  u16* AsD0 = As + (w * 32) * 32;
  u16* AsD1 = As + (w * 32 + 16) * 32;
  u16* BsD0 = Bs + (w * 32) * 32;
  u16* BsD1 = Bs + (w * 32 + 16) * 32;

  const int wm = (w & 1) * 64;
  const int wn = (w >> 1) * 64;
  const int rl = lane & 15;
  const int q = lane >> 4;

  f32x4 acc[4][4] = {};

  for (int k0 = 0; k0 < K; k0 += 32) {
    __syncthreads();
    GLDS16(Ag0 + k0, AsD0);
    GLDS16(Ag1 + k0, AsD1);
    GLDS16(Bg0 + k0, BsD0);
    GLDS16(Bg1 + k0, BsD1);
    __syncthreads();
    bf16x8 af[4], bfv[4];
#pragma unroll
    for (int i = 0; i < 4; ++i) {
      int ra = wm + i * 16 + rl;
      af[i] = *(const bf16x8*)(As + ra * 32 + ((q ^ (ra & 3)) << 3));
      int rb = wn + i * 16 + rl;
      bfv[i] = *(const bf16x8*)(Bs + rb * 32 + ((q ^ (rb & 3)) << 3));
    }
#pragma unroll
    for (int i = 0; i < 4; ++i)
#pragma unroll
      for (int j = 0; j < 4; ++j)
        acc[i][j] = MFMA_BF16(af[i], bfv[j], acc[i][j]);
  }

#pragma unroll
  for (int i = 0; i < 4; ++i)
#pragma unroll
    for (int j = 0; j < 4; ++j)
#pragma unroll
      for (int r = 0; r < 4; ++r) {
        int gm = m_base + wm + i * 16 + q * 4 + r;
        int gn = n_base + wn + j * 16 + rl;
        int orow = ((gm & 511) << 6) | (gm >> 9);
        outp[(size_t)orow * 1024 + gn] = f2b(acc[i][j][r]);
      }
}

// ---------------- per-step kernel: L0 step k + L1 step (k-1) ----------------
// 64 blocks x 256 threads. Blocks 0..31: L0 slice s (32 cols); 32..63: L1.
// Wave wid handles batch rows [wid*16, wid*16+16) for full K=1024 (no combine).
// W_hh slice (32x1024 bf16, 64KB) staged to LDS per launch (L2-hot).
// h rings: packed u32 (bf16 hi | bf16 lo<<16), depth 2, plain loads/stores —
// coherence from kernel-dispatch boundaries.
__global__ __launch_bounds__(256) void step_kernel(
    const u16* __restrict__ whh0, const u16* __restrict__ whh1,
    const u16* __restrict__ wih1, const u16* __restrict__ pre0,
    const float* __restrict__ bv0, const float* __restrict__ bv1,
    u32* __restrict__ h0ring, u32* __restrict__ h1ring, int k) {
  __shared__ u16 Whh[32 * 1024];  // 64KB

  const int bid = blockIdx.x;
  const bool isL0 = bid < 32;
  const int t = isL0 ? k : (k - 1);
  if (isL0) { if (t >= 512) return; } else { if (t < 0) return; }
  const int s = bid & 31;
  const int c0 = s * 32;
  const int tid = threadIdx.x;

  // stage W_hh slice (rows c0..c0+31), 16B-chunk XOR swizzle by (n&7)
  {
    const u16* wsrc = isL0 ? whh0 : whh1;
#pragma unroll
    for (int i = 0; i < 16; ++i) {
      int idx = i * 256 + tid;
      int n = idx >> 7;
      int c = idx & 127;
      bf16x8 v = *(const bf16x8*)(wsrc + (size_t)(c0 + n) * 1024 + c * 8);
      *(bf16x8*)(Whh + n * 1024 + ((c ^ (n & 7)) << 3)) = v;
    }
  }
  __syncthreads();

  const int lane = tid & 63;
  const int wid = tid >> 6;
  const int rl = lane & 15;
  const int q = lane >> 4;
  const int b0 = wid * 16;  // this wave's 16 batch rows

  const float* bv = isL0 ? bv0 : bv1;
  const float bias0 = bv[c0 + rl];
  const float bias1 = bv[c0 + 16 + rl];

  const int arow = (b0 + rl) * 1024 + q * 8;       // A-read base (row, k-chunk)
  const int wrow = (b0 + q * 4) * 1024 + c0 + rl;  // C-write base

  const u16* w0p = Whh + rl * 1024;
  const u16* w1p = Whh + (16 + rl) * 1024;

  f32x4 acc0 = {0.f, 0.f, 0.f, 0.f}, acc1 = {0.f, 0.f, 0.f, 0.f};

  if (isL0) {
    // h0(t) = relu(pre0[t] + h0(t-1) @ W0^T + b0), hi+lo split A
    const u32* ap = h0ring + ((t + 1) & 1) * 65536 + arow;
#pragma unroll 4
    for (int kt = 0; kt < 32; ++kt) {
      u32x4 d0 = *(const u32x4*)(ap + kt * 32);
      u32x4 d1 = *(const u32x4*)(ap + kt * 32 + 4);
      bf16x8 ah = hi_frag(d0, d1);
      bf16x8 al = lo_frag(d0, d1);
      int cc = ((kt * 4 + q) ^ (rl & 7)) << 3;
      bf16x8 w0 = *(const bf16x8*)(w0p + cc);
      bf16x8 w1 = *(const bf16x8*)(w1p + cc);
      acc0 = MFMA_BF16(ah, w0, acc0); acc0 = MFMA_BF16(al, w0, acc0);
      acc1 = MFMA_BF16(ah, w1, acc1); acc1 = MFMA_BF16(al, w1, acc1);
    }
    const u16* pt = pre0 + (size_t)t * 65536 + wrow;
    u32* wb = h0ring + (t & 1) * 65536 + wrow;
#pragma unroll
    for (int r = 0; r < 4; ++r) {
      float v0 = acc0[r] + b2f(pt[r * 1024]) + bias0;
      v0 = fmaxf(v0, 0.f);
      u16 h = f2b(v0);
      u16 l = f2b(v0 - b2f(h));
      wb[r * 1024] = (u32)h | ((u32)l << 16);
      float v1 = acc1[r] + b2f(pt[r * 1024 + 16]) + bias1;
      v1 = fmaxf(v1, 0.f);
      u16 h2 = f2b(v1);
      u16 l2 = f2b(v1 - b2f(h2));
      wb[r * 1024 + 16] = (u32)h2 | ((u32)l2 << 16);
    }
  } else {
    // h1(t) = relu(h0(t) @ Wih1^T (hi) + h1(t-1) @ W1^T (hi+lo) + b1)
    const u32* ap = h1ring + ((t + 1) & 1) * 65536 + arow;  // h1(t-1)
    const u32* ep = h0ring + (t & 1) * 65536 + arow;        // h0(t)
    const u16* wi0 = wih1 + (size_t)(c0 + rl) * 1024 + q * 8;
    const u16* wi1 = wi0 + 16 * 1024;
#pragma unroll 4
    for (int kt = 0; kt < 32; ++kt) {
      u32x4 d0 = *(const u32x4*)(ap + kt * 32);
      u32x4 d1 = *(const u32x4*)(ap + kt * 32 + 4);
      u32x4 e0 = *(const u32x4*)(ep + kt * 32);
      u32x4 e1 = *(const u32x4*)(ep + kt * 32 + 4);
      bf16x8 a1h = hi_frag(d0, d1);
      bf16x8 a1l = lo_frag(d0, d1);
      bf16x8 a0h = hi_frag(e0, e1);
      int cc = ((kt * 4 + q) ^ (rl & 7)) << 3;
      bf16x8 wh0 = *(const bf16x8*)(w0p + cc);
      bf16x8 wh1 = *(const bf16x8*)(w1p + cc);
      bf16x8 wi0f = *(const bf16x8*)(wi0 + kt * 32);
      bf16x8 wi1f = *(const bf16x8*)(wi1 + kt * 32);
      acc0 = MFMA_BF16(a1h, wh0, acc0); acc0 = MFMA_BF16(a1l, wh0, acc0);
      acc0 = MFMA_BF16(a0h, wi0f, acc0);
      acc1 = MFMA_BF16(a1h, wh1, acc1); acc1 = MFMA_BF16(a1l, wh1, acc1);
      acc1 = MFMA_BF16(a0h, wi1f, acc1);
    }
    u32* wb = h1ring + (t & 1) * 65536 + wrow;
#pragma unroll
    for (int r = 0; r < 4; ++r) {
      float v0 = acc0[r] + bias0;
      v0 = fmaxf(v0, 0.f);
      u16 h = f2b(v0);
      u16 l = f2b(v0 - b2f(h));
      wb[r * 1024] = (u32)h | ((u32)l << 16);
      float v1 = acc1[r] + bias1;
      v1 = fmaxf(v1, 0.f);
      u16 h2 = f2b(v1);
      u16 l2 = f2b(v1 - b2f(h2));
      wb[r * 1024 + 16] = (u32)h2 | ((u32)l2 << 16);
    }
  }
}

// ---------------- head: logits = h1_last @ w_lin^T + b_lin ----------------
__global__ __launch_bounds__(64) void logits_kernel(const u32* __restrict__ hpk,  // packed [64][1024]
                                                    const u16* __restrict__ wl,   // [1008][1024]
                                                    const float* __restrict__ blin,
                                                    float* __restrict__ lg) {     // [64][1008]
  const int wgn = blockIdx.x;  // 0..62
  const int lane = threadIdx.x;
  const int rl = lane & 15;
  const int q = lane >> 4;
  f32x4 acc[4] = {};
  const u16* brow = wl + (size_t)(wgn * 16 + rl) * 1024 + q * 8;
  for (int kt = 0; kt < 32; ++kt) {
    bf16x8 bfv = *(const bf16x8*)(brow + kt * 32);
#pragma unroll
    for (int mi = 0; mi < 4; ++mi) {
      const u32* hp = hpk + (mi * 16 + rl) * 1024 + kt * 32 + q * 8;
      u32x4 d0 = *(const u32x4*)hp;
      u32x4 d1 = *(const u32x4*)(hp + 4);
      acc[mi] = MFMA_BF16(hi_frag(d0, d1), bfv, acc[mi]);
      acc[mi] = MFMA_BF16(lo_frag(d0, d1), bfv, acc[mi]);
    }
  }
  int col = wgn * 16 + rl;
  float bb = (col < 1000) ? blin[col] : 0.f;
#pragma unroll
  for (int mi = 0; mi < 4; ++mi)
#pragma unroll
    for (int r = 0; r < 4; ++r) {
      int row = mi * 16 + q * 4 + r;
      lg[row * 1008 + col] = acc[mi][r] + bb;
    }
}

__global__ __launch_bounds__(64) void lsm_kernel(const float* __restrict__ lg,
                                                 float* __restrict__ outp) {
  const int b = blockIdx.x;
  const int lane = threadIdx.x;
  float x[16];
  float m = -1e30f;
#pragma unroll
  for (int i = 0; i < 16; ++i) {
    int o = lane + i * 64;
    x[i] = (o < 1000) ? lg[b * 1008 + o] : -1e30f;
    m = fmaxf(m, x[i]);
  }
  for (int s = 32; s > 0; s >>= 1) m = fmaxf(m, __shfl_xor(m, s, 64));
  float sum = 0.f;
#pragma unroll
  for (int i = 0; i < 16; ++i) sum += expf(x[i] - m);
  for (int s = 32; s > 0; s >>= 1) sum += __shfl_xor(sum, s, 64);
  float lse = m + logf(sum);
#pragma unroll
  for (int i = 0; i < 16; ++i) {
    int o = lane + i * 64;
    if (o < 1000) outp[b * 1000 + o] = x[i] - lse;
  }
}

// ---------------- launch ----------------
extern "C" void kernel_launch(void* const* d_in, const int* in_sizes, int n_in,
                              void* d_out, int out_size, void* d_ws, size_t ws_size,
                              hipStream_t stream) {
  (void)in_sizes; (void)n_in; (void)out_size;
  const int B = 64, T = 512, I = 256, H = 1024, O = 1000;

  const float* x = (const float*)d_in[0];
  const float* w_ih0 = (const float*)d_in[1];
  const float* w_hh0 = (const float*)d_in[2];
  const float* b_ih0 = (const float*)d_in[3];
  const float* b_hh0 = (const float*)d_in[4];
  const float* w_ih1 = (const float*)d_in[5];
  const float* w_hh1 = (const float*)d_in[6];
  const float* b_ih1 = (const float*)d_in[7];
  const float* b_hh1 = (const float*)d_in[8];
  const float* w_lin = (const float*)d_in[9];
  const float* b_lin = (const float*)d_in[10];

  size_t off = 0;
  char* ws = (char*)d_ws;
  auto take = [&](size_t bytes) -> void* {
    void* p = ws + off;
    off += (bytes + 255) & ~(size_t)255;
    return p;
  };
  u16* pre = (u16*)take((size_t)T * B * H * 2);   // 64MB
  u16* xbf = (u16*)take((size_t)B * T * I * 2);   // 16MB
  u16* wih0b = (u16*)take((size_t)H * I * 2);
  u16* whh0b = (u16*)take((size_t)H * H * 2);
  u16* wih1b = (u16*)take((size_t)H * H * 2);
  u16* whh1b = (u16*)take((size_t)H * H * 2);
  u16* wlinb = (u16*)take((size_t)1008 * H * 2);
  float* bv0 = (float*)take((size_t)H * 4);
  float* bv1 = (float*)take((size_t)H * 4);
  u32* h0ring = (u32*)take((size_t)2 * B * H * 4);  // packed hi|lo, ping-pong
  u32* h1ring = (u32*)take((size_t)2 * B * H * 4);
  float* lgt = (float*)take((size_t)B * 1008 * 4);
  if (off > ws_size) return;

  // casts
  cast_kernel<<<(B * T * I / 4) / 256, 256, 0, stream>>>(x, xbf, B * T * I / 4);
  cast_kernel<<<(H * I / 4) / 256, 256, 0, stream>>>(w_ih0, wih0b, H * I / 4);
  cast_kernel<<<(H * H / 4) / 256, 256, 0, stream>>>(w_hh0, whh0b, H * H / 4);
  cast_kernel<<<(H * H / 4) / 256, 256, 0, stream>>>(w_ih1, wih1b, H * H / 4);
  cast_kernel<<<(H * H / 4) / 256, 256, 0, stream>>>(w_hh1, whh1b, H * H / 4);
  cast_kernel<<<(O * H / 4) / 256, 256, 0, stream>>>(w_lin, wlinb, O * H / 4);
  bias_kernel<<<4, 256, 0, stream>>>(b_ih0, b_hh0, bv0, H);
  bias_kernel<<<4, 256, 0, stream>>>(b_ih1, b_hh1, bv1, H);

  // zero slot 1 of both rings (h(-1) = 0)
  init_ring_kernel<<<256, 256, 0, stream>>>(h0ring, h1ring);

  gemm_pre<<<dim3((B * T / 128) * (H / 128)), 256, 0, stream>>>(xbf, wih0b, pre, I);

  // the scan: one launch per step; kernel k does L0(k) and L1(k-1)
  for (int k = 0; k <= 512; ++k) {
    step_kernel<<<64, 256, 0, stream>>>(whh0b, whh1b, wih1b, pre, bv0, bv1,
                                        h0ring, h1ring, k);
  }

  // h1(511) is in ring slot 511&1 = 1
  logits_kernel<<<63, 64, 0, stream>>>(h1ring + 65536, wlinb, b_lin, lgt);
  lsm_kernel<<<64, 64, 0, stream>>>(lgt, (float*)d_out);
}